// Round 1
// baseline (6672.151 us; speedup 1.0000x reference)
//
#include <hip/hip_runtime.h>
#include <hip/hip_bf16.h>
#include <math.h>

#define BB 4
#define QTOT 5376
#define DMM 256
#define NHEADS 8
#define HDIM 32
#define NPTS 4
#define NLVLS 3
#define BQ (BB*QTOT)   // 21504

// ---------------------------------------------------------------------------
// Transpose (B,C,H,W) -> (B, HW, C) slice of (B, QTOT, C), optional +embed[c]
// grid: (HW/32, C/32, B), block: (32,8)
// ---------------------------------------------------------------------------
__global__ __launch_bounds__(256) void transpose_in(
    const float* __restrict__ src, const float* __restrict__ emb,
    float* __restrict__ dst, int HW, int qstart)
{
  __shared__ float t[32][33];
  int hw0 = blockIdx.x * 32, c0 = blockIdx.y * 32, b = blockIdx.z;
  int tx = threadIdx.x, ty = threadIdx.y;
  const float* s = src + ((size_t)b * DMM + c0) * HW + hw0;
#pragma unroll
  for (int j = 0; j < 4; j++)
    t[ty * 4 + j][tx] = s[(size_t)(ty * 4 + j) * HW + tx];
  __syncthreads();
  float e = emb ? emb[c0 + tx] : 0.0f;
  float* d = dst + ((size_t)b * QTOT + qstart + hw0) * DMM + c0;
#pragma unroll
  for (int j = 0; j < 4; j++)
    d[(size_t)(ty * 4 + j) * DMM + tx] = t[tx][ty * 4 + j] + e;
}

// ---------------------------------------------------------------------------
// C[M,N] = (A (+A2)) @ W^T + bias, optional relu.  A:(M,K) W:(N,K) row-major.
// 64x64 tile, 256 threads, 4x4 per thread, K-step 16. M%64==0, K%16==0.
// ---------------------------------------------------------------------------
__global__ __launch_bounds__(256) void gemm_nt(
    const float* __restrict__ A, const float* __restrict__ A2,
    const float* __restrict__ W, const float* __restrict__ bias,
    float* __restrict__ C, int M, int N, int K, int relu)
{
  __shared__ float As[64][17];
  __shared__ float Ws[64][17];
  int m0 = blockIdx.x * 64, n0 = blockIdx.y * 64;
  int tid = threadIdx.x;
  int lr = tid >> 2, lc4 = (tid & 3) * 4;
  int tx = tid & 15, ty = tid >> 4;
  float acc[4][4] = {};
  const float* Ap  = A + (size_t)(m0 + lr) * K + lc4;
  const float* A2p = A2 ? A2 + (size_t)(m0 + lr) * K + lc4 : nullptr;
  bool wvalid = (n0 + lr) < N;
  const float* Wp = W + (size_t)(n0 + lr) * K + lc4;

  for (int k0 = 0; k0 < K; k0 += 16) {
    float4 av = *(const float4*)(Ap + k0);
    if (A2p) {
      float4 a2 = *(const float4*)(A2p + k0);
      av.x += a2.x; av.y += a2.y; av.z += a2.z; av.w += a2.w;
    }
    float4 wv = wvalid ? *(const float4*)(Wp + k0) : make_float4(0.f, 0.f, 0.f, 0.f);
    __syncthreads();
    As[lr][lc4 + 0] = av.x; As[lr][lc4 + 1] = av.y;
    As[lr][lc4 + 2] = av.z; As[lr][lc4 + 3] = av.w;
    Ws[lr][lc4 + 0] = wv.x; Ws[lr][lc4 + 1] = wv.y;
    Ws[lr][lc4 + 2] = wv.z; Ws[lr][lc4 + 3] = wv.w;
    __syncthreads();
#pragma unroll
    for (int kk = 0; kk < 16; kk++) {
      float a[4], bfr[4];
#pragma unroll
      for (int i = 0; i < 4; i++) a[i] = As[ty * 4 + i][kk];
#pragma unroll
      for (int j = 0; j < 4; j++) bfr[j] = Ws[tx * 4 + j][kk];
#pragma unroll
      for (int i = 0; i < 4; i++)
#pragma unroll
        for (int j = 0; j < 4; j++) acc[i][j] += a[i] * bfr[j];
    }
  }
#pragma unroll
  for (int i = 0; i < 4; i++) {
    int m = m0 + ty * 4 + i;
#pragma unroll
    for (int j = 0; j < 4; j++) {
      int n = n0 + tx * 4 + j;
      if (n < N) {
        float v = acc[i][j] + bias[n];
        if (relu) v = fmaxf(v, 0.0f);
        C[(size_t)m * N + n] = v;
      }
    }
  }
}

// ---------------------------------------------------------------------------
// Deformable-attention sampling. One block per (b,q), 256 thr = 8 heads x 32 d.
// value:(B,QTOT,256)  off:(B,QTOT,192)  awraw:(B,QTOT,96) -> attn:(B,QTOT,256)
// ---------------------------------------------------------------------------
__global__ __launch_bounds__(256) void msda_sample(
    const float* __restrict__ value, const float* __restrict__ off,
    const float* __restrict__ awraw, float* __restrict__ attn)
{
  int bq = blockIdx.x;
  int b = bq / QTOT, q = bq % QTOT;
  int tid = threadIdx.x;
  int h = tid >> 5, d = tid & 31;

  __shared__ float soff[192];
  __shared__ float saw[96];
  if (tid < 192) soff[tid] = off[(size_t)bq * 192 + tid];
  if (tid < 96)  saw[tid]  = awraw[(size_t)bq * 96 + tid];
  __syncthreads();

  // softmax over the 12 (level,point) weights of this head (redundant per d)
  float e[12];
  float mx = -1e30f;
#pragma unroll
  for (int t = 0; t < 12; t++) mx = fmaxf(mx, saw[h * 12 + t]);
  float den = 0.f;
#pragma unroll
  for (int t = 0; t < 12; t++) { e[t] = __expf(saw[h * 12 + t] - mx); den += e[t]; }
  float inv = 1.0f / den;

  // reference point of this query (uniform across block)
  int qq, Wq, Hq;
  if (q < 4096)      { qq = q;        Hq = 64; Wq = 64; }
  else if (q < 5120) { qq = q - 4096; Hq = 32; Wq = 32; }
  else               { qq = q - 5120; Hq = 16; Wq = 16; }
  float refx = ((qq % Wq) + 0.5f) / Wq;
  float refy = ((qq / Wq) + 0.5f) / Hq;

  const int   LH[3] = {64, 32, 16};
  const int   LW[3] = {64, 32, 16};
  const int   LS[3] = {0, 4096, 5120};

  float acc = 0.f;
  const float* vbase = value + (size_t)b * QTOT * DMM + h * HDIM + d;
#pragma unroll
  for (int l = 0; l < NLVLS; l++) {
    int Wl = LW[l], Hl = LH[l], st = LS[l];
#pragma unroll
    for (int p = 0; p < NPTS; p++) {
      int oi = (((h * NLVLS + l) * NPTS) + p) * 2;
      float lx = refx + soff[oi]     / (float)Wl;
      float ly = refy + soff[oi + 1] / (float)Hl;
      float xf = lx * Wl - 0.5f;
      float yf = ly * Hl - 0.5f;
      float x0f = floorf(xf), y0f = floorf(yf);
      float fx = xf - x0f, fy = yf - y0f;
      int x0 = (int)x0f, y0 = (int)y0f;
      float aw = e[l * NPTS + p] * inv;

      float w00 = (1.f - fx) * (1.f - fy) * aw;
      float w10 = fx * (1.f - fy) * aw;
      float w01 = (1.f - fx) * fy * aw;
      float w11 = fx * fy * aw;

      if (x0 >= 0 && x0 < Wl && y0 >= 0 && y0 < Hl)
        acc += w00 * vbase[(size_t)(st + y0 * Wl + x0) * DMM];
      if (x0 + 1 >= 0 && x0 + 1 < Wl && y0 >= 0 && y0 < Hl)
        acc += w10 * vbase[(size_t)(st + y0 * Wl + x0 + 1) * DMM];
      if (x0 >= 0 && x0 < Wl && y0 + 1 >= 0 && y0 + 1 < Hl)
        acc += w01 * vbase[(size_t)(st + (y0 + 1) * Wl + x0) * DMM];
      if (x0 + 1 >= 0 && x0 + 1 < Wl && y0 + 1 >= 0 && y0 + 1 < Hl)
        acc += w11 * vbase[(size_t)(st + (y0 + 1) * Wl + x0 + 1) * DMM];
    }
  }
  attn[(size_t)bq * DMM + tid] = acc;
}

// ---------------------------------------------------------------------------
// x = LayerNorm(x + t) * g + b   (row = 256 elements, one block per row)
// ---------------------------------------------------------------------------
__global__ __launch_bounds__(256) void add_ln(
    float* __restrict__ x, const float* __restrict__ t,
    const float* __restrict__ g, const float* __restrict__ bta)
{
  int row = blockIdx.x;
  int tid = threadIdx.x;
  float v = x[(size_t)row * DMM + tid] + t[(size_t)row * DMM + tid];
  float s = v, s2 = v * v;
#pragma unroll
  for (int o = 32; o > 0; o >>= 1) {
    s  += __shfl_down(s,  o, 64);
    s2 += __shfl_down(s2, o, 64);
  }
  __shared__ float red[2][4];
  int wave = tid >> 6, lane = tid & 63;
  if (lane == 0) { red[0][wave] = s; red[1][wave] = s2; }
  __syncthreads();
  float ts  = red[0][0] + red[0][1] + red[0][2] + red[0][3];
  float ts2 = red[1][0] + red[1][1] + red[1][2] + red[1][3];
  float mean = ts * (1.0f / DMM);
  float var  = ts2 * (1.0f / DMM) - mean * mean;
  float sc = rsqrtf(var + 1e-5f);
  x[(size_t)row * DMM + tid] = (v - mean) * sc * g[tid] + bta[tid];
}

// ---------------------------------------------------------------------------
extern "C" void kernel_launch(void* const* d_in, const int* in_sizes, int n_in,
                              void* d_out, int out_size, void* d_ws, size_t ws_size,
                              hipStream_t stream)
{
  const float* src[3] = {(const float*)d_in[0], (const float*)d_in[1], (const float*)d_in[2]};
  const float* pin[3] = {(const float*)d_in[3], (const float*)d_in[4], (const float*)d_in[5]};
  const float* lvl_emb = (const float*)d_in[6];
  const float* off_w = (const float*)d_in[7];
  const float* off_b = (const float*)d_in[8];
  const float* aw_w  = (const float*)d_in[9];
  const float* aw_b  = (const float*)d_in[10];
  const float* val_w = (const float*)d_in[11];
  const float* val_b = (const float*)d_in[12];
  const float* out_w = (const float*)d_in[13];
  const float* out_b = (const float*)d_in[14];
  const float* ln1_g = (const float*)d_in[15];
  const float* ln1_b = (const float*)d_in[16];
  const float* ffn1_w = (const float*)d_in[17];
  const float* ffn1_b = (const float*)d_in[18];
  const float* ffn2_w = (const float*)d_in[19];
  const float* ffn2_b = (const float*)d_in[20];
  const float* ln2_g = (const float*)d_in[21];
  const float* ln2_b = (const float*)d_in[22];

  float* x = (float*)d_out;                       // (B, QTOT, 256)
  float* posb = (float*)d_ws;                     // (B, QTOT, 256)
  float* valb = posb + (size_t)BQ * 256;          // (B, QTOT, 256) value / t
  float* offb = valb + (size_t)BQ * 256;          // (B, QTOT, 192)
  float* awb  = offb + (size_t)BQ * 192;          // (B, QTOT, 96)
  float* attnb = awb + (size_t)BQ * 96;           // (B, QTOT, 256)
  float* hb   = attnb + (size_t)BQ * 256;         // (5376, 1024) ffn chunk

  const int HWs[3] = {4096, 1024, 256};
  const int starts[3] = {0, 4096, 5120};

  // build x and pos
  for (int l = 0; l < 3; l++) {
    dim3 g(HWs[l] / 32, DMM / 32, BB), blk(32, 8);
    transpose_in<<<g, blk, 0, stream>>>(src[l], nullptr, x, HWs[l], starts[l]);
    transpose_in<<<g, blk, 0, stream>>>(pin[l], lvl_emb + l * 256, posb, HWs[l], starts[l]);
  }

  const int CH = 5376;            // ffn M-chunk
  for (int i = 0; i < 6; i++) {
    const float* vW = val_w + (size_t)i * 256 * 256;
    const float* oW = off_w + (size_t)i * 192 * 256;
    const float* aW = aw_w  + (size_t)i * 96 * 256;
    const float* uW = out_w + (size_t)i * 256 * 256;
    const float* f1W = ffn1_w + (size_t)i * 1024 * 256;
    const float* f2W = ffn2_w + (size_t)i * 256 * 1024;

    gemm_nt<<<dim3(BQ / 64, 4), 256, 0, stream>>>(x, nullptr, vW, val_b + i * 256, valb, BQ, 256, 256, 0);
    gemm_nt<<<dim3(BQ / 64, 3), 256, 0, stream>>>(x, posb, oW, off_b + i * 192, offb, BQ, 192, 256, 0);
    gemm_nt<<<dim3(BQ / 64, 2), 256, 0, stream>>>(x, posb, aW, aw_b + i * 96, awb, BQ, 96, 256, 0);
    msda_sample<<<BQ, 256, 0, stream>>>(valb, offb, awb, attnb);
    gemm_nt<<<dim3(BQ / 64, 4), 256, 0, stream>>>(attnb, nullptr, uW, out_b + i * 256, valb, BQ, 256, 256, 0);
    add_ln<<<BQ, 256, 0, stream>>>(x, valb, ln1_g + i * 256, ln1_b + i * 256);

    for (int c = 0; c < BQ / CH; c++) {
      gemm_nt<<<dim3(CH / 64, 16), 256, 0, stream>>>(x + (size_t)c * CH * 256, nullptr,
          f1W, ffn1_b + i * 1024, hb, CH, 1024, 256, 1);
      gemm_nt<<<dim3(CH / 64, 4), 256, 0, stream>>>(hb, nullptr,
          f2W, ffn2_b + i * 256, valb + (size_t)c * CH * 256, CH, 256, 1024, 0);
    }
    add_ln<<<BQ, 256, 0, stream>>>(x, valb, ln2_g + i * 256, ln2_b + i * 256);
  }
}

// Round 2
// 2875.146 us; speedup vs baseline: 2.3206x; 2.3206x over previous
//
#include <hip/hip_runtime.h>
#include <hip/hip_bf16.h>
#include <math.h>

#define BB 4
#define QTOT 5376
#define DMM 256
#define NHEADS 8
#define HDIM 32
#define NPTS 4
#define NLVLS 3
#define BQ (BB*QTOT)   // 21504

typedef short bf16x8 __attribute__((ext_vector_type(8)));
typedef float f32x4  __attribute__((ext_vector_type(4)));

__device__ __forceinline__ unsigned short f2b(float f) {
  unsigned int u = __float_as_uint(f);
  unsigned int r = (u + 0x7FFFu + ((u >> 16) & 1u)) >> 16;   // RNE
  return (unsigned short)r;
}

// ---------------------------------------------------------------------------
// Transpose (B,C,H,W) -> (B, HW, C) slice of (B, QTOT, C), optional +embed[c]
// grid: (HW/32, C/32, B), block: (32,8)
// ---------------------------------------------------------------------------
__global__ __launch_bounds__(256) void transpose_in(
    const float* __restrict__ src, const float* __restrict__ emb,
    float* __restrict__ dst, int HW, int qstart)
{
  __shared__ float t[32][33];
  int hw0 = blockIdx.x * 32, c0 = blockIdx.y * 32, b = blockIdx.z;
  int tx = threadIdx.x, ty = threadIdx.y;
  const float* s = src + ((size_t)b * DMM + c0) * HW + hw0;
#pragma unroll
  for (int j = 0; j < 4; j++)
    t[ty * 4 + j][tx] = s[(size_t)(ty * 4 + j) * HW + tx];
  __syncthreads();
  float e = emb ? emb[c0 + tx] : 0.0f;
  float* d = dst + ((size_t)b * QTOT + qstart + hw0) * DMM + c0;
#pragma unroll
  for (int j = 0; j < 4; j++)
    d[(size_t)(ty * 4 + j) * DMM + tx] = t[tx][ty * 4 + j] + e;
}

// ---------------------------------------------------------------------------
// C[M,N] = (A (+A2)) @ W^T + bias, optional relu, bf16 MFMA.
// A:(M,K) fp32, W:(N,K) fp32 — both converted to bf16 during LDS staging.
// 128x128 tile, 256 thr (4 waves, each 64x64 = 4x4 frags of 16x16x32).
// M % 128 == 0, K % 32 == 0. N arbitrary (masked).
// ---------------------------------------------------------------------------
__global__ __launch_bounds__(256) void gemm_mfma(
    const float* __restrict__ A, const float* __restrict__ A2,
    const float* __restrict__ W, const float* __restrict__ bias,
    float* __restrict__ C, int M, int N, int K, int relu)
{
  // 32 k-cols + 8 pad = 40 ushorts = 80 B row stride (odd multiple of 16B:
  // stride-walk covers all 8 bank-quads for ds_read_b128)
  __shared__ unsigned short As[128][40];
  __shared__ unsigned short Ws[128][40];

  int m0 = blockIdx.x * 128, n0 = blockIdx.y * 128;
  int tid = threadIdx.x;
  int wave = tid >> 6, lane = tid & 63;
  int wrr = (wave >> 1) * 64;       // wave row offset in tile
  int wcc = (wave & 1) * 64;        // wave col offset in tile
  int lr = lane & 15;               // fragment row/col within 16
  int lk = (lane >> 4) * 8;         // k start within 32

  // staging: thread t handles rows (t>>3)+i*32, float4 col (t&7)
  int sr = tid >> 3, sc = tid & 7;

  f32x4 acc[4][4] = {};

  for (int k0 = 0; k0 < K; k0 += 32) {
    // global loads into regs (fp32)
    float4 av[4], wv[4];
#pragma unroll
    for (int i = 0; i < 4; i++) {
      int r = sr + i * 32;
      av[i] = *(const float4*)(A + (size_t)(m0 + r) * K + k0 + sc * 4);
      if (A2) {
        float4 a2 = *(const float4*)(A2 + (size_t)(m0 + r) * K + k0 + sc * 4);
        av[i].x += a2.x; av[i].y += a2.y; av[i].z += a2.z; av[i].w += a2.w;
      }
      int nrow = n0 + r;
      wv[i] = (nrow < N) ? *(const float4*)(W + (size_t)nrow * K + k0 + sc * 4)
                         : make_float4(0.f, 0.f, 0.f, 0.f);
    }
    __syncthreads();   // previous iteration's MFMA reads done
#pragma unroll
    for (int i = 0; i < 4; i++) {
      int r = sr + i * 32;
      ushort4 ab, wb;
      ab.x = f2b(av[i].x); ab.y = f2b(av[i].y); ab.z = f2b(av[i].z); ab.w = f2b(av[i].w);
      wb.x = f2b(wv[i].x); wb.y = f2b(wv[i].y); wb.z = f2b(wv[i].z); wb.w = f2b(wv[i].w);
      *(ushort4*)&As[r][sc * 4] = ab;
      *(ushort4*)&Ws[r][sc * 4] = wb;
    }
    __syncthreads();

    bf16x8 af[4], bfv[4];
#pragma unroll
    for (int m = 0; m < 4; m++)
      af[m] = *(const bf16x8*)&As[wrr + m * 16 + lr][lk];
#pragma unroll
    for (int n = 0; n < 4; n++)
      bfv[n] = *(const bf16x8*)&Ws[wcc + n * 16 + lr][lk];
#pragma unroll
    for (int m = 0; m < 4; m++)
#pragma unroll
      for (int n = 0; n < 4; n++)
        acc[m][n] = __builtin_amdgcn_mfma_f32_16x16x32_bf16(af[m], bfv[n], acc[m][n], 0, 0, 0);
  }

  // epilogue: C/D layout col=lane&15, row=(lane>>4)*4+reg
#pragma unroll
  for (int n = 0; n < 4; n++) {
    int col = n0 + wcc + n * 16 + lr;
    if (col >= N) continue;
    float bv = bias[col];
#pragma unroll
    for (int m = 0; m < 4; m++) {
      int row0 = m0 + wrr + m * 16 + (lane >> 4) * 4;
#pragma unroll
      for (int j = 0; j < 4; j++) {
        float v = acc[m][n][j] + bv;
        if (relu) v = fmaxf(v, 0.0f);
        C[(size_t)(row0 + j) * N + col] = v;
      }
    }
  }
}

// ---------------------------------------------------------------------------
// Deformable-attention sampling. One block per (b,q), 256 thr = 8 heads x 32 d.
// ---------------------------------------------------------------------------
__global__ __launch_bounds__(256) void msda_sample(
    const float* __restrict__ value, const float* __restrict__ off,
    const float* __restrict__ awraw, float* __restrict__ attn)
{
  int bq = blockIdx.x;
  int b = bq / QTOT, q = bq % QTOT;
  int tid = threadIdx.x;
  int h = tid >> 5, d = tid & 31;

  __shared__ float soff[192];
  __shared__ float saw[96];
  if (tid < 192) soff[tid] = off[(size_t)bq * 192 + tid];
  if (tid < 96)  saw[tid]  = awraw[(size_t)bq * 96 + tid];
  __syncthreads();

  float e[12];
  float mx = -1e30f;
#pragma unroll
  for (int t = 0; t < 12; t++) mx = fmaxf(mx, saw[h * 12 + t]);
  float den = 0.f;
#pragma unroll
  for (int t = 0; t < 12; t++) { e[t] = __expf(saw[h * 12 + t] - mx); den += e[t]; }
  float inv = 1.0f / den;

  int qq, Wq, Hq;
  if (q < 4096)      { qq = q;        Hq = 64; Wq = 64; }
  else if (q < 5120) { qq = q - 4096; Hq = 32; Wq = 32; }
  else               { qq = q - 5120; Hq = 16; Wq = 16; }
  float refx = ((qq % Wq) + 0.5f) / Wq;
  float refy = ((qq / Wq) + 0.5f) / Hq;

  const int LH[3] = {64, 32, 16};
  const int LW[3] = {64, 32, 16};
  const int LS[3] = {0, 4096, 5120};

  float acc = 0.f;
  const float* vbase = value + (size_t)b * QTOT * DMM + h * HDIM + d;
#pragma unroll
  for (int l = 0; l < NLVLS; l++) {
    int Wl = LW[l], Hl = LH[l], st = LS[l];
#pragma unroll
    for (int p = 0; p < NPTS; p++) {
      int oi = (((h * NLVLS + l) * NPTS) + p) * 2;
      float lx = refx + soff[oi]     / (float)Wl;
      float ly = refy + soff[oi + 1] / (float)Hl;
      float xf = lx * Wl - 0.5f;
      float yf = ly * Hl - 0.5f;
      float x0f = floorf(xf), y0f = floorf(yf);
      float fx = xf - x0f, fy = yf - y0f;
      int x0 = (int)x0f, y0 = (int)y0f;
      float aw = e[l * NPTS + p] * inv;

      float w00 = (1.f - fx) * (1.f - fy) * aw;
      float w10 = fx * (1.f - fy) * aw;
      float w01 = (1.f - fx) * fy * aw;
      float w11 = fx * fy * aw;

      if (x0 >= 0 && x0 < Wl && y0 >= 0 && y0 < Hl)
        acc += w00 * vbase[(size_t)(st + y0 * Wl + x0) * DMM];
      if (x0 + 1 >= 0 && x0 + 1 < Wl && y0 >= 0 && y0 < Hl)
        acc += w10 * vbase[(size_t)(st + y0 * Wl + x0 + 1) * DMM];
      if (x0 >= 0 && x0 < Wl && y0 + 1 >= 0 && y0 + 1 < Hl)
        acc += w01 * vbase[(size_t)(st + (y0 + 1) * Wl + x0) * DMM];
      if (x0 + 1 >= 0 && x0 + 1 < Wl && y0 + 1 >= 0 && y0 + 1 < Hl)
        acc += w11 * vbase[(size_t)(st + (y0 + 1) * Wl + x0 + 1) * DMM];
    }
  }
  attn[(size_t)bq * DMM + tid] = acc;
}

// ---------------------------------------------------------------------------
// x = LayerNorm(x + t) * g + b   (row = 256 elements, one block per row)
// ---------------------------------------------------------------------------
__global__ __launch_bounds__(256) void add_ln(
    float* __restrict__ x, const float* __restrict__ t,
    const float* __restrict__ g, const float* __restrict__ bta)
{
  int row = blockIdx.x;
  int tid = threadIdx.x;
  float v = x[(size_t)row * DMM + tid] + t[(size_t)row * DMM + tid];
  float s = v, s2 = v * v;
#pragma unroll
  for (int o = 32; o > 0; o >>= 1) {
    s  += __shfl_down(s,  o, 64);
    s2 += __shfl_down(s2, o, 64);
  }
  __shared__ float red[2][4];
  int wave = tid >> 6, lane = tid & 63;
  if (lane == 0) { red[0][wave] = s; red[1][wave] = s2; }
  __syncthreads();
  float ts  = red[0][0] + red[0][1] + red[0][2] + red[0][3];
  float ts2 = red[1][0] + red[1][1] + red[1][2] + red[1][3];
  float mean = ts * (1.0f / DMM);
  float var  = ts2 * (1.0f / DMM) - mean * mean;
  float sc = rsqrtf(var + 1e-5f);
  x[(size_t)row * DMM + tid] = (v - mean) * sc * g[tid] + bta[tid];
}

// ---------------------------------------------------------------------------
extern "C" void kernel_launch(void* const* d_in, const int* in_sizes, int n_in,
                              void* d_out, int out_size, void* d_ws, size_t ws_size,
                              hipStream_t stream)
{
  const float* src[3] = {(const float*)d_in[0], (const float*)d_in[1], (const float*)d_in[2]};
  const float* pin[3] = {(const float*)d_in[3], (const float*)d_in[4], (const float*)d_in[5]};
  const float* lvl_emb = (const float*)d_in[6];
  const float* off_w = (const float*)d_in[7];
  const float* off_b = (const float*)d_in[8];
  const float* aw_w  = (const float*)d_in[9];
  const float* aw_b  = (const float*)d_in[10];
  const float* val_w = (const float*)d_in[11];
  const float* val_b = (const float*)d_in[12];
  const float* out_w = (const float*)d_in[13];
  const float* out_b = (const float*)d_in[14];
  const float* ln1_g = (const float*)d_in[15];
  const float* ln1_b = (const float*)d_in[16];
  const float* ffn1_w = (const float*)d_in[17];
  const float* ffn1_b = (const float*)d_in[18];
  const float* ffn2_w = (const float*)d_in[19];
  const float* ffn2_b = (const float*)d_in[20];
  const float* ln2_g = (const float*)d_in[21];
  const float* ln2_b = (const float*)d_in[22];

  float* x = (float*)d_out;                       // (B, QTOT, 256)
  float* posb = (float*)d_ws;                     // (B, QTOT, 256)
  float* valb = posb + (size_t)BQ * 256;          // (B, QTOT, 256) value / t
  float* offb = valb + (size_t)BQ * 256;          // (B, QTOT, 192)
  float* awb  = offb + (size_t)BQ * 192;          // (B, QTOT, 96)
  float* attnb = awb + (size_t)BQ * 96;           // (B, QTOT, 256)
  float* hb   = attnb + (size_t)BQ * 256;         // (5376, 1024) ffn chunk

  const int HWs[3] = {4096, 1024, 256};
  const int starts[3] = {0, 4096, 5120};

  for (int l = 0; l < 3; l++) {
    dim3 g(HWs[l] / 32, DMM / 32, BB), blk(32, 8);
    transpose_in<<<g, blk, 0, stream>>>(src[l], nullptr, x, HWs[l], starts[l]);
    transpose_in<<<g, blk, 0, stream>>>(pin[l], lvl_emb + l * 256, posb, HWs[l], starts[l]);
  }

  const int CH = 5376;            // ffn M-chunk (42 x 128)
  for (int i = 0; i < 6; i++) {
    const float* vW = val_w + (size_t)i * 256 * 256;
    const float* oW = off_w + (size_t)i * 192 * 256;
    const float* aW = aw_w  + (size_t)i * 96 * 256;
    const float* uW = out_w + (size_t)i * 256 * 256;
    const float* f1W = ffn1_w + (size_t)i * 1024 * 256;
    const float* f2W = ffn2_w + (size_t)i * 256 * 1024;

    gemm_mfma<<<dim3(BQ / 128, 2), 256, 0, stream>>>(x, nullptr, vW, val_b + i * 256, valb, BQ, 256, 256, 0);
    gemm_mfma<<<dim3(BQ / 128, 2), 256, 0, stream>>>(x, posb, oW, off_b + i * 192, offb, BQ, 192, 256, 0);
    gemm_mfma<<<dim3(BQ / 128, 1), 256, 0, stream>>>(x, posb, aW, aw_b + i * 96, awb, BQ, 96, 256, 0);
    msda_sample<<<BQ, 256, 0, stream>>>(valb, offb, awb, attnb);
    gemm_mfma<<<dim3(BQ / 128, 2), 256, 0, stream>>>(attnb, nullptr, uW, out_b + i * 256, valb, BQ, 256, 256, 0);
    add_ln<<<BQ, 256, 0, stream>>>(x, valb, ln1_g + i * 256, ln1_b + i * 256);

    for (int c = 0; c < BQ / CH; c++) {
      gemm_mfma<<<dim3(CH / 128, 8), 256, 0, stream>>>(x + (size_t)c * CH * 256, nullptr,
          f1W, ffn1_b + i * 1024, hb, CH, 1024, 256, 1);
      gemm_mfma<<<dim3(CH / 128, 2), 256, 0, stream>>>(hb, nullptr,
          f2W, ffn2_b + i * 256, valb + (size_t)c * CH * 256, CH, 256, 1024, 0);
    }
    add_ln<<<BQ, 256, 0, stream>>>(x, valb, ln2_g + i * 256, ln2_b + i * 256);
  }
}

// Round 3
// 1850.762 us; speedup vs baseline: 3.6051x; 1.5535x over previous
//
#include <hip/hip_runtime.h>
#include <hip/hip_bf16.h>
#include <math.h>

#define BB 4
#define QTOT 5376
#define DMM 256
#define NHEADS 8
#define HDIM 32
#define NPTS 4
#define NLVLS 3
#define BQ (BB*QTOT)   // 21504

typedef short bf16x8 __attribute__((ext_vector_type(8)));
typedef unsigned short u16x8 __attribute__((ext_vector_type(8)));
typedef float f32x4  __attribute__((ext_vector_type(4)));

__device__ __forceinline__ unsigned short f2b(float f) {
  unsigned int u = __float_as_uint(f);
  unsigned int r = (u + 0x7FFFu + ((u >> 16) & 1u)) >> 16;   // RNE
  return (unsigned short)r;
}

// ---------------------------------------------------------------------------
// Transpose (B,C,H,W) -> (B, HW, C) slice of (B, QTOT, C), optional +embed[c]
// ---------------------------------------------------------------------------
__global__ __launch_bounds__(256) void transpose_in(
    const float* __restrict__ src, const float* __restrict__ emb,
    float* __restrict__ dst, int HW, int qstart)
{
  __shared__ float t[32][33];
  int hw0 = blockIdx.x * 32, c0 = blockIdx.y * 32, b = blockIdx.z;
  int tx = threadIdx.x, ty = threadIdx.y;
  const float* s = src + ((size_t)b * DMM + c0) * HW + hw0;
#pragma unroll
  for (int j = 0; j < 4; j++)
    t[ty * 4 + j][tx] = s[(size_t)(ty * 4 + j) * HW + tx];
  __syncthreads();
  float e = emb ? emb[c0 + tx] : 0.0f;
  float* d = dst + ((size_t)b * QTOT + qstart + hw0) * DMM + c0;
#pragma unroll
  for (int j = 0; j < 4; j++)
    d[(size_t)(ty * 4 + j) * DMM + tx] = t[tx][ty * 4 + j] + e;
}

// fp32 -> bf16 elementwise (n multiple of 4)
__global__ __launch_bounds__(256) void conv_b(
    const float* __restrict__ s, unsigned short* __restrict__ d, int n4)
{
  int i = blockIdx.x * 256 + threadIdx.x;
  if (i >= n4) return;
  float4 v = ((const float4*)s)[i];
  ushort4 o;
  o.x = f2b(v.x); o.y = f2b(v.y); o.z = f2b(v.z); o.w = f2b(v.w);
  ((ushort4*)d)[i] = o;
}

// qb = bf16(x + pos)  (n4 = n/4)
__global__ __launch_bounds__(256) void make_q(
    const float* __restrict__ x, const float* __restrict__ pos,
    unsigned short* __restrict__ qb, int n4)
{
  int i = blockIdx.x * 256 + threadIdx.x;
  if (i >= n4) return;
  float4 a = ((const float4*)x)[i];
  float4 p = ((const float4*)pos)[i];
  ushort4 o;
  o.x = f2b(a.x + p.x); o.y = f2b(a.y + p.y);
  o.z = f2b(a.z + p.z); o.w = f2b(a.w + p.w);
  ((ushort4*)qb)[i] = o;
}

// ---------------------------------------------------------------------------
// C[M,N] = A @ W^T + bias. A:(M,K) bf16, W:(N,K) bf16.
// 128x128 tile, 256 thr (4 waves, each 64x64 = 4x4 frags of 16x16x32).
// M % 128 == 0, K % 32 == 0, N masked. flags: 1=relu, 2=bf16 output.
// ---------------------------------------------------------------------------
__global__ __launch_bounds__(256) void gemm_bf(
    const unsigned short* __restrict__ A, const unsigned short* __restrict__ W,
    const float* __restrict__ bias, void* __restrict__ Cout,
    int M, int N, int K, int flags)
{
  __shared__ unsigned short As[128][40];   // 80B row stride
  __shared__ unsigned short Ws[128][40];

  int m0 = blockIdx.x * 128, n0 = blockIdx.y * 128;
  int tid = threadIdx.x;
  int wave = tid >> 6, lane = tid & 63;
  int wrr = (wave >> 1) * 64;
  int wcc = (wave & 1) * 64;
  int lr = lane & 15;
  int lk = (lane >> 4) * 8;
  int sr = tid >> 2, sc = tid & 3;       // staging: row, 16B chunk

  f32x4 acc[4][4] = {};
  const u16x8 zero8 = {};

  for (int k0 = 0; k0 < K; k0 += 32) {
    u16x8 a0 = *(const u16x8*)(A + (size_t)(m0 + sr) * K + k0 + sc * 8);
    u16x8 a1 = *(const u16x8*)(A + (size_t)(m0 + sr + 64) * K + k0 + sc * 8);
    int n_r0 = n0 + sr, n_r1 = n0 + sr + 64;
    u16x8 w0 = (n_r0 < N) ? *(const u16x8*)(W + (size_t)n_r0 * K + k0 + sc * 8) : zero8;
    u16x8 w1 = (n_r1 < N) ? *(const u16x8*)(W + (size_t)n_r1 * K + k0 + sc * 8) : zero8;
    __syncthreads();
    *(u16x8*)&As[sr][sc * 8]      = a0;
    *(u16x8*)&As[sr + 64][sc * 8] = a1;
    *(u16x8*)&Ws[sr][sc * 8]      = w0;
    *(u16x8*)&Ws[sr + 64][sc * 8] = w1;
    __syncthreads();

    bf16x8 af[4], bfv[4];
#pragma unroll
    for (int m = 0; m < 4; m++)
      af[m] = *(const bf16x8*)&As[wrr + m * 16 + lr][lk];
#pragma unroll
    for (int n = 0; n < 4; n++)
      bfv[n] = *(const bf16x8*)&Ws[wcc + n * 16 + lr][lk];
#pragma unroll
    for (int m = 0; m < 4; m++)
#pragma unroll
      for (int n = 0; n < 4; n++)
        acc[m][n] = __builtin_amdgcn_mfma_f32_16x16x32_bf16(af[m], bfv[n], acc[m][n], 0, 0, 0);
  }

  int relu = flags & 1, bfout = flags & 2;
  float* C32 = (float*)Cout;
  unsigned short* C16 = (unsigned short*)Cout;
#pragma unroll
  for (int n = 0; n < 4; n++) {
    int col = n0 + wcc + n * 16 + lr;
    if (col >= N) continue;
    float bv = bias[col];
#pragma unroll
    for (int m = 0; m < 4; m++) {
      int row0 = m0 + wrr + m * 16 + (lane >> 4) * 4;
#pragma unroll
      for (int j = 0; j < 4; j++) {
        float v = acc[m][n][j] + bv;
        if (relu) v = fmaxf(v, 0.0f);
        if (bfout) C16[(size_t)(row0 + j) * N + col] = f2b(v);
        else       C32[(size_t)(row0 + j) * N + col] = v;
      }
    }
  }
}

// ---------------------------------------------------------------------------
// Deformable sampling. Block = 4 queries x 64 thr (8 heads x 8 d-groups of 4).
// value:(B,QTOT,256) f32; off/awraw f32; attn16:(B,QTOT,256) bf16 out.
// ---------------------------------------------------------------------------
__global__ __launch_bounds__(256) void msda_sample(
    const float* __restrict__ value, const float* __restrict__ off,
    const float* __restrict__ awraw, unsigned short* __restrict__ attn16)
{
  int tid = threadIdx.x;
  int qi = tid >> 6, tq = tid & 63;
  int h = tq >> 3, dg = tq & 7;
  int bq = blockIdx.x * 4 + qi;
  int b = bq / QTOT, q = bq % QTOT;

  __shared__ float soff[4][192];
  __shared__ float saw[4][96];
  for (int i = tq; i < 192; i += 64) soff[qi][i] = off[(size_t)bq * 192 + i];
  for (int i = tq; i < 96; i += 64)  saw[qi][i]  = awraw[(size_t)bq * 96 + i];
  __syncthreads();

  float e[12];
  float mx = -1e30f;
#pragma unroll
  for (int t = 0; t < 12; t++) mx = fmaxf(mx, saw[qi][h * 12 + t]);
  float den = 0.f;
#pragma unroll
  for (int t = 0; t < 12; t++) { e[t] = __expf(saw[qi][h * 12 + t] - mx); den += e[t]; }
  float inv = 1.0f / den;

  int qq, Wq, Hq;
  if (q < 4096)      { qq = q;        Hq = 64; Wq = 64; }
  else if (q < 5120) { qq = q - 4096; Hq = 32; Wq = 32; }
  else               { qq = q - 5120; Hq = 16; Wq = 16; }
  float refx = ((qq % Wq) + 0.5f) / Wq;
  float refy = ((qq / Wq) + 0.5f) / Hq;

  const int LH[3] = {64, 32, 16};
  const int LW[3] = {64, 32, 16};
  const int LS[3] = {0, 4096, 5120};

  float4 acc = make_float4(0.f, 0.f, 0.f, 0.f);
  const float* vbase = value + (size_t)b * QTOT * DMM + h * HDIM + dg * 4;
#pragma unroll
  for (int l = 0; l < NLVLS; l++) {
    int Wl = LW[l], Hl = LH[l], st = LS[l];
#pragma unroll
    for (int p = 0; p < NPTS; p++) {
      int oi = (((h * NLVLS + l) * NPTS) + p) * 2;
      float xf = (refx + soff[qi][oi]     / (float)Wl) * Wl - 0.5f;
      float yf = (refy + soff[qi][oi + 1] / (float)Hl) * Hl - 0.5f;
      float x0f = floorf(xf), y0f = floorf(yf);
      float fx = xf - x0f, fy = yf - y0f;
      int x0 = (int)x0f, y0 = (int)y0f;
      float aw = e[l * NPTS + p] * inv;

      float w00 = (1.f - fx) * (1.f - fy) * aw;
      float w10 = fx * (1.f - fy) * aw;
      float w01 = (1.f - fx) * fy * aw;
      float w11 = fx * fy * aw;

      bool xv0 = (x0 >= 0) & (x0 < Wl), xv1 = (x0 + 1 >= 0) & (x0 + 1 < Wl);
      bool yv0 = (y0 >= 0) & (y0 < Hl), yv1 = (y0 + 1 >= 0) & (y0 + 1 < Hl);
#define GATHER(wgt, xi, yi)                                                    \
      { const float4 g = *(const float4*)(vbase + (size_t)(st + (yi) * Wl + (xi)) * DMM); \
        acc.x += (wgt) * g.x; acc.y += (wgt) * g.y;                            \
        acc.z += (wgt) * g.z; acc.w += (wgt) * g.w; }
      if (xv0 & yv0) GATHER(w00, x0,     y0)
      if (xv1 & yv0) GATHER(w10, x0 + 1, y0)
      if (xv0 & yv1) GATHER(w01, x0,     y0 + 1)
      if (xv1 & yv1) GATHER(w11, x0 + 1, y0 + 1)
#undef GATHER
    }
  }
  ushort4 o;
  o.x = f2b(acc.x); o.y = f2b(acc.y); o.z = f2b(acc.z); o.w = f2b(acc.w);
  *(ushort4*)(attn16 + (size_t)bq * DMM + h * HDIM + dg * 4) = o;
}

// ---------------------------------------------------------------------------
// x = LayerNorm(x + t) * g + b ; also writes xb = bf16(x)
// ---------------------------------------------------------------------------
__global__ __launch_bounds__(256) void add_ln(
    float* __restrict__ x, const float* __restrict__ t,
    const float* __restrict__ g, const float* __restrict__ bta,
    unsigned short* __restrict__ xb)
{
  int row = blockIdx.x;
  int tid = threadIdx.x;
  float v = x[(size_t)row * DMM + tid] + t[(size_t)row * DMM + tid];
  float s = v, s2 = v * v;
#pragma unroll
  for (int o = 32; o > 0; o >>= 1) {
    s  += __shfl_down(s,  o, 64);
    s2 += __shfl_down(s2, o, 64);
  }
  __shared__ float red[2][4];
  int wave = tid >> 6, lane = tid & 63;
  if (lane == 0) { red[0][wave] = s; red[1][wave] = s2; }
  __syncthreads();
  float ts  = red[0][0] + red[0][1] + red[0][2] + red[0][3];
  float ts2 = red[1][0] + red[1][1] + red[1][2] + red[1][3];
  float mean = ts * (1.0f / DMM);
  float var  = ts2 * (1.0f / DMM) - mean * mean;
  float sc = rsqrtf(var + 1e-5f);
  float o = (v - mean) * sc * g[tid] + bta[tid];
  x[(size_t)row * DMM + tid] = o;
  xb[(size_t)row * DMM + tid] = f2b(o);
}

// ---------------------------------------------------------------------------
extern "C" void kernel_launch(void* const* d_in, const int* in_sizes, int n_in,
                              void* d_out, int out_size, void* d_ws, size_t ws_size,
                              hipStream_t stream)
{
  const float* src[3] = {(const float*)d_in[0], (const float*)d_in[1], (const float*)d_in[2]};
  const float* pin[3] = {(const float*)d_in[3], (const float*)d_in[4], (const float*)d_in[5]};
  const float* lvl_emb = (const float*)d_in[6];
  const float* off_w = (const float*)d_in[7];
  const float* off_b = (const float*)d_in[8];
  const float* aw_w  = (const float*)d_in[9];
  const float* aw_b  = (const float*)d_in[10];
  const float* val_w = (const float*)d_in[11];
  const float* val_b = (const float*)d_in[12];
  const float* out_w = (const float*)d_in[13];
  const float* out_b = (const float*)d_in[14];
  const float* ln1_g = (const float*)d_in[15];
  const float* ln1_b = (const float*)d_in[16];
  const float* ffn1_w = (const float*)d_in[17];
  const float* ffn1_b = (const float*)d_in[18];
  const float* ffn2_w = (const float*)d_in[19];
  const float* ffn2_b = (const float*)d_in[20];
  const float* ln2_g = (const float*)d_in[21];
  const float* ln2_b = (const float*)d_in[22];

  float* x = (float*)d_out;                                  // (B,QTOT,256) f32

  char* wsp = (char*)d_ws;
  float* posb = (float*)wsp;                 wsp += (size_t)BQ * 256 * 4;
  float* valb = (float*)wsp;                 wsp += (size_t)BQ * 256 * 4;  // value / t
  float* offb = (float*)wsp;                 wsp += (size_t)BQ * 192 * 4;
  float* awb  = (float*)wsp;                 wsp += (size_t)BQ * 96 * 4;
  unsigned short* xb    = (unsigned short*)wsp; wsp += (size_t)BQ * 256 * 2;
  unsigned short* qb    = (unsigned short*)wsp; wsp += (size_t)BQ * 256 * 2;
  unsigned short* attnb = (unsigned short*)wsp; wsp += (size_t)BQ * 256 * 2;
  unsigned short* hb    = attnb;  // aliased: disjoint lifetimes (5376*1024 bf16)
  unsigned short* wb    = (unsigned short*)wsp; wsp += (size_t)4374528 * 2;

  // bf16 weight blocks
  unsigned short* vWb  = wb;
  unsigned short* oWb  = vWb + (size_t)6 * 256 * 256;
  unsigned short* aWb  = oWb + (size_t)6 * 192 * 256;
  unsigned short* uWb  = aWb + (size_t)6 * 96 * 256;
  unsigned short* f1Wb = uWb + (size_t)6 * 256 * 256;
  unsigned short* f2Wb = f1Wb + (size_t)6 * 1024 * 256;

  conv_b<<<(6 * 65536 / 4 + 255) / 256, 256, 0, stream>>>(val_w, vWb, 6 * 65536 / 4);
  conv_b<<<(6 * 49152 / 4 + 255) / 256, 256, 0, stream>>>(off_w, oWb, 6 * 49152 / 4);
  conv_b<<<(6 * 24576 / 4 + 255) / 256, 256, 0, stream>>>(aw_w,  aWb, 6 * 24576 / 4);
  conv_b<<<(6 * 65536 / 4 + 255) / 256, 256, 0, stream>>>(out_w, uWb, 6 * 65536 / 4);
  conv_b<<<(6 * 262144 / 4 + 255) / 256, 256, 0, stream>>>(ffn1_w, f1Wb, 6 * 262144 / 4);
  conv_b<<<(6 * 262144 / 4 + 255) / 256, 256, 0, stream>>>(ffn2_w, f2Wb, 6 * 262144 / 4);

  const int HWs[3] = {4096, 1024, 256};
  const int starts[3] = {0, 4096, 5120};
  for (int l = 0; l < 3; l++) {
    dim3 g(HWs[l] / 32, DMM / 32, BB), blk(32, 8);
    transpose_in<<<g, blk, 0, stream>>>(src[l], nullptr, x, HWs[l], starts[l]);
    transpose_in<<<g, blk, 0, stream>>>(pin[l], lvl_emb + l * 256, posb, HWs[l], starts[l]);
  }
  conv_b<<<(BQ * 256 / 4 + 255) / 256, 256, 0, stream>>>(x, xb, BQ * 256 / 4);

  const int CH = 5376;            // ffn M-chunk (42 x 128)
  for (int i = 0; i < 6; i++) {
    make_q<<<(BQ * 256 / 4 + 255) / 256, 256, 0, stream>>>(x, posb, qb, BQ * 256 / 4);

    gemm_bf<<<dim3(BQ / 128, 2), 256, 0, stream>>>(xb, vWb + (size_t)i * 65536,
        val_b + i * 256, valb, BQ, 256, 256, 0);
    gemm_bf<<<dim3(BQ / 128, 2), 256, 0, stream>>>(qb, oWb + (size_t)i * 49152,
        off_b + i * 192, offb, BQ, 192, 256, 0);
    gemm_bf<<<dim3(BQ / 128, 1), 256, 0, stream>>>(qb, aWb + (size_t)i * 24576,
        aw_b + i * 96, awb, BQ, 96, 256, 0);
    msda_sample<<<BQ / 4, 256, 0, stream>>>(valb, offb, awb, attnb);
    gemm_bf<<<dim3(BQ / 128, 2), 256, 0, stream>>>(attnb, uWb + (size_t)i * 65536,
        out_b + i * 256, valb, BQ, 256, 256, 0);
    add_ln<<<BQ, 256, 0, stream>>>(x, valb, ln1_g + i * 256, ln1_b + i * 256, xb);

    for (int c = 0; c < BQ / CH; c++) {
      gemm_bf<<<dim3(CH / 128, 8), 256, 0, stream>>>(xb + (size_t)c * CH * 256,
          f1Wb + (size_t)i * 262144, ffn1_b + i * 1024, hb, CH, 1024, 256, 1 | 2);
      gemm_bf<<<dim3(CH / 128, 2), 256, 0, stream>>>(hb,
          f2Wb + (size_t)i * 262144, ffn2_b + i * 256, valb + (size_t)c * CH * 256,
          CH, 256, 1024, 0);
    }
    add_ln<<<BQ, 256, 0, stream>>>(x, valb, ln2_g + i * 256, ln2_b + i * 256, xb);
  }
}

// Round 4
// 1186.386 us; speedup vs baseline: 5.6239x; 1.5600x over previous
//
#include <hip/hip_runtime.h>
#include <hip/hip_bf16.h>
#include <math.h>

#define BB 4
#define QTOT 5376
#define DMM 256
#define NHEADS 8
#define HDIM 32
#define NPTS 4
#define NLVLS 3
#define BQ (BB*QTOT)   // 21504
#define NOA 288        // packed off(192)+aw(96)

typedef short bf16x8 __attribute__((ext_vector_type(8)));
typedef unsigned short u16x8 __attribute__((ext_vector_type(8)));
typedef float f32x4  __attribute__((ext_vector_type(4)));

__device__ __forceinline__ unsigned short f2b(float f) {
  unsigned int u = __float_as_uint(f);
  unsigned int r = (u + 0x7FFFu + ((u >> 16) & 1u)) >> 16;   // RNE
  return (unsigned short)r;
}
__device__ __forceinline__ float b2f(unsigned short u) {
  return __uint_as_float(((unsigned int)u) << 16);
}
__device__ __forceinline__ ushort4 f2b4(float4 v) {
  ushort4 o; o.x = f2b(v.x); o.y = f2b(v.y); o.z = f2b(v.z); o.w = f2b(v.w);
  return o;
}

__device__ __forceinline__ void gload16(const void* g, void* l) {
  __builtin_amdgcn_global_load_lds(
      (const __attribute__((address_space(1))) void*)g,
      (__attribute__((address_space(3))) void*)l, 16, 0, 0);
}

// ---------------------------------------------------------------------------
// Transpose (B,C,H,W) -> (B, HW, C) slice of (B, QTOT, C), optional +embed[c]
// ---------------------------------------------------------------------------
__global__ __launch_bounds__(256) void transpose_in(
    const float* __restrict__ src, const float* __restrict__ emb,
    float* __restrict__ dst, int HW, int qstart)
{
  __shared__ float t[32][33];
  int hw0 = blockIdx.x * 32, c0 = blockIdx.y * 32, b = blockIdx.z;
  int tx = threadIdx.x, ty = threadIdx.y;
  const float* s = src + ((size_t)b * DMM + c0) * HW + hw0;
#pragma unroll
  for (int j = 0; j < 4; j++)
    t[ty * 4 + j][tx] = s[(size_t)(ty * 4 + j) * HW + tx];
  __syncthreads();
  float e = emb ? emb[c0 + tx] : 0.0f;
  float* d = dst + ((size_t)b * QTOT + qstart + hw0) * DMM + c0;
#pragma unroll
  for (int j = 0; j < 4; j++)
    d[(size_t)(ty * 4 + j) * DMM + tx] = t[tx][ty * 4 + j] + e;
}

// fp32 -> bf16 elementwise (vector of 4)
__global__ __launch_bounds__(256) void conv_b(
    const float* __restrict__ s, unsigned short* __restrict__ d, int n4)
{
  int i = blockIdx.x * 256 + threadIdx.x;
  if (i >= n4) return;
  ((ushort4*)d)[i] = f2b4(((const float4*)s)[i]);
}

// pack off_w/aw_w -> (6, 288, 256) bf16
__global__ __launch_bounds__(256) void pack_oa(
    const float* __restrict__ offw, const float* __restrict__ aww,
    unsigned short* __restrict__ dst)
{
  int i = blockIdx.x * 256 + threadIdx.x;          // group of 4 cols
  if (i >= 6 * NOA * 64) return;
  int c4 = i & 63;
  int row = (i >> 6) % NOA;
  int l = i / (NOA * 64);
  const float* src = (row < 192)
      ? offw + ((size_t)l * 192 + row) * 256
      : aww  + ((size_t)l * 96 + (row - 192)) * 256;
  float4 v = ((const float4*)src)[c4];
  ((ushort4*)dst)[i] = f2b4(v);
}

__global__ __launch_bounds__(256) void pack_oa_bias(
    const float* __restrict__ offb, const float* __restrict__ awb,
    float* __restrict__ dst)
{
  int i = blockIdx.x * 256 + threadIdx.x;
  if (i >= 6 * NOA) return;
  int row = i % NOA, l = i / NOA;
  dst[i] = (row < 192) ? offb[l * 192 + row] : awb[l * 96 + (row - 192)];
}

// xb = bf16(x), qb = bf16(x+pos)
__global__ __launch_bounds__(256) void prep(
    const float* __restrict__ x, const float* __restrict__ pos,
    unsigned short* __restrict__ xb, unsigned short* __restrict__ qb, int n4)
{
  int i = blockIdx.x * 256 + threadIdx.x;
  if (i >= n4) return;
  float4 a = ((const float4*)x)[i];
  float4 p = ((const float4*)pos)[i];
  ((ushort4*)xb)[i] = f2b4(a);
  float4 q = make_float4(a.x + p.x, a.y + p.y, a.z + p.z, a.w + p.w);
  ((ushort4*)qb)[i] = f2b4(q);
}

// ---------------------------------------------------------------------------
// C[M,N] = A @ W^T + bias. A:(M,K) bf16, W:(N,K) bf16 (rows beyond N readable).
// 128x128 tile, 256 thr, global_load_lds staging, linear LDS (m97 structure).
// M % 128 == 0, K % 32 == 0. flags: 1=relu, 2=bf16 output.
// ---------------------------------------------------------------------------
__global__ __launch_bounds__(256) void gemm_bf(
    const unsigned short* __restrict__ A, const unsigned short* __restrict__ W,
    const float* __restrict__ bias, void* __restrict__ Cout,
    int M, int N, int K, int flags)
{
  __shared__ unsigned short As[128][32];
  __shared__ unsigned short Ws[128][32];

  int m0 = blockIdx.x * 128, n0 = blockIdx.y * 128;
  int tid = threadIdx.x;
  int wave = tid >> 6, lane = tid & 63;
  int wrr = (wave >> 1) * 64;
  int wcc = (wave & 1) * 64;
  int lr = lane & 15;
  int lk = (lane >> 4) * 8;

  // staging geometry: wave covers 32 rows (2 issues of 16 rows);
  // lane -> row = lane>>2, 16B chunk = lane&3
  int srow = lane >> 2, schunk = (lane & 3) * 8;
  const unsigned short* Ag = A + (size_t)(m0 + wave * 32 + srow) * K + schunk;
  const unsigned short* Wg = W + (size_t)(n0 + wave * 32 + srow) * K + schunk;
  unsigned short* Al0 = &As[wave * 32][0];
  unsigned short* Al1 = &As[wave * 32 + 16][0];
  unsigned short* Wl0 = &Ws[wave * 32][0];
  unsigned short* Wl1 = &Ws[wave * 32 + 16][0];

  f32x4 acc[4][4] = {};

  for (int k0 = 0; k0 < K; k0 += 32) {
    __syncthreads();          // all prior ds_reads done before DMA overwrite
    gload16(Ag + k0, Al0);
    gload16(Ag + (size_t)16 * K + k0, Al1);
    gload16(Wg + k0, Wl0);
    gload16(Wg + (size_t)16 * K + k0, Wl1);
    __syncthreads();          // DMA drained (vmcnt) + all waves see data

    bf16x8 af[4], bfv[4];
#pragma unroll
    for (int m = 0; m < 4; m++)
      af[m] = *(const bf16x8*)&As[wrr + m * 16 + lr][lk];
#pragma unroll
    for (int n = 0; n < 4; n++)
      bfv[n] = *(const bf16x8*)&Ws[wcc + n * 16 + lr][lk];
#pragma unroll
    for (int m = 0; m < 4; m++)
#pragma unroll
      for (int n = 0; n < 4; n++)
        acc[m][n] = __builtin_amdgcn_mfma_f32_16x16x32_bf16(af[m], bfv[n], acc[m][n], 0, 0, 0);
  }

  int relu = flags & 1, bfout = flags & 2;
  float* C32 = (float*)Cout;
  unsigned short* C16 = (unsigned short*)Cout;
#pragma unroll
  for (int n = 0; n < 4; n++) {
    int col = n0 + wcc + n * 16 + lr;
    if (col >= N) continue;
    float bv = bias[col];
#pragma unroll
    for (int m = 0; m < 4; m++) {
      int row0 = m0 + wrr + m * 16 + (lane >> 4) * 4;
#pragma unroll
      for (int j = 0; j < 4; j++) {
        float v = acc[m][n][j] + bv;
        if (relu) v = fmaxf(v, 0.0f);
        if (bfout) C16[(size_t)(row0 + j) * N + col] = f2b(v);
        else       C32[(size_t)(row0 + j) * N + col] = v;
      }
    }
  }
}

// ---------------------------------------------------------------------------
// Deformable sampling. Block = 4 queries x 64 thr (8 heads x 8 d-groups of 4).
// value:(B,QTOT,256) bf16; offaw:(B,QTOT,288) f32; attn16 bf16 out.
// ---------------------------------------------------------------------------
__global__ __launch_bounds__(256) void msda_sample(
    const unsigned short* __restrict__ value, const float* __restrict__ offaw,
    unsigned short* __restrict__ attn16)
{
  int tid = threadIdx.x;
  int qi = tid >> 6, tq = tid & 63;
  int h = tq >> 3, dg = tq & 7;
  int bq = blockIdx.x * 4 + qi;
  int b = bq / QTOT, q = bq % QTOT;

  __shared__ float soff[4][192];
  __shared__ float saw[4][96];
  for (int i = tq; i < 192; i += 64) soff[qi][i] = offaw[(size_t)bq * NOA + i];
  for (int i = tq; i < 96; i += 64)  saw[qi][i]  = offaw[(size_t)bq * NOA + 192 + i];
  __syncthreads();

  float e[12];
  float mx = -1e30f;
#pragma unroll
  for (int t = 0; t < 12; t++) mx = fmaxf(mx, saw[qi][h * 12 + t]);
  float den = 0.f;
#pragma unroll
  for (int t = 0; t < 12; t++) { e[t] = __expf(saw[qi][h * 12 + t] - mx); den += e[t]; }
  float inv = 1.0f / den;

  int qq, Wq, Hq;
  if (q < 4096)      { qq = q;        Hq = 64; Wq = 64; }
  else if (q < 5120) { qq = q - 4096; Hq = 32; Wq = 32; }
  else               { qq = q - 5120; Hq = 16; Wq = 16; }
  float refx = ((qq % Wq) + 0.5f) / Wq;
  float refy = ((qq / Wq) + 0.5f) / Hq;

  const int LH[3] = {64, 32, 16};
  const int LW[3] = {64, 32, 16};
  const int LS[3] = {0, 4096, 5120};

  float4 acc = make_float4(0.f, 0.f, 0.f, 0.f);
  const unsigned short* vbase = value + (size_t)b * QTOT * DMM + h * HDIM + dg * 4;
#pragma unroll
  for (int l = 0; l < NLVLS; l++) {
    int Wl = LW[l], Hl = LH[l], st = LS[l];
#pragma unroll
    for (int p = 0; p < NPTS; p++) {
      int oi = (((h * NLVLS + l) * NPTS) + p) * 2;
      float xf = (refx + soff[qi][oi]     / (float)Wl) * Wl - 0.5f;
      float yf = (refy + soff[qi][oi + 1] / (float)Hl) * Hl - 0.5f;
      float x0f = floorf(xf), y0f = floorf(yf);
      float fx = xf - x0f, fy = yf - y0f;
      int x0 = (int)x0f, y0 = (int)y0f;
      float aw = e[l * NPTS + p] * inv;

      float w00 = (1.f - fx) * (1.f - fy) * aw;
      float w10 = fx * (1.f - fy) * aw;
      float w01 = (1.f - fx) * fy * aw;
      float w11 = fx * fy * aw;

      bool xv0 = (x0 >= 0) & (x0 < Wl), xv1 = (x0 + 1 >= 0) & (x0 + 1 < Wl);
      bool yv0 = (y0 >= 0) & (y0 < Hl), yv1 = (y0 + 1 >= 0) & (y0 + 1 < Hl);
#define GATHER(wgt, xi, yi)                                                    \
      { const ushort4 g = *(const ushort4*)(vbase + (size_t)(st + (yi) * Wl + (xi)) * DMM); \
        acc.x += (wgt) * b2f(g.x); acc.y += (wgt) * b2f(g.y);                  \
        acc.z += (wgt) * b2f(g.z); acc.w += (wgt) * b2f(g.w); }
      if (xv0 & yv0) GATHER(w00, x0,     y0)
      if (xv1 & yv0) GATHER(w10, x0 + 1, y0)
      if (xv0 & yv1) GATHER(w01, x0,     y0 + 1)
      if (xv1 & yv1) GATHER(w11, x0 + 1, y0 + 1)
#undef GATHER
    }
  }
  *(ushort4*)(attn16 + (size_t)bq * DMM + h * HDIM + dg * 4) = f2b4(acc);
}

// ---------------------------------------------------------------------------
// x = LayerNorm(x + t)*g + b ; xb = bf16(x); optional qb = bf16(x + pos)
// one wave per row, lane handles 4 floats; grid = BQ/4 blocks of 256.
// ---------------------------------------------------------------------------
__global__ __launch_bounds__(256) void add_ln4(
    float* __restrict__ x, const float* __restrict__ t,
    const float* __restrict__ g, const float* __restrict__ bta,
    unsigned short* __restrict__ xb,
    const float* __restrict__ pos, unsigned short* __restrict__ qb)
{
  int wave = threadIdx.x >> 6, lane = threadIdx.x & 63;
  int row = blockIdx.x * 4 + wave;
  size_t base = (size_t)row * DMM + lane * 4;
  float4 a = *(const float4*)(x + base);
  float4 tv = *(const float4*)(t + base);
  float4 v = make_float4(a.x + tv.x, a.y + tv.y, a.z + tv.z, a.w + tv.w);
  float s  = v.x + v.y + v.z + v.w;
  float s2 = v.x * v.x + v.y * v.y + v.z * v.z + v.w * v.w;
#pragma unroll
  for (int o = 32; o > 0; o >>= 1) {
    s  += __shfl_xor(s,  o, 64);
    s2 += __shfl_xor(s2, o, 64);
  }
  float mean = s * (1.0f / DMM);
  float var  = s2 * (1.0f / DMM) - mean * mean;
  float sc = rsqrtf(var + 1e-5f);
  float4 gv = *(const float4*)(g + lane * 4);
  float4 bv = *(const float4*)(bta + lane * 4);
  float4 o4 = make_float4((v.x - mean) * sc * gv.x + bv.x,
                          (v.y - mean) * sc * gv.y + bv.y,
                          (v.z - mean) * sc * gv.z + bv.z,
                          (v.w - mean) * sc * gv.w + bv.w);
  *(float4*)(x + base) = o4;
  *(ushort4*)(xb + base) = f2b4(o4);
  if (qb) {
    float4 p = *(const float4*)(pos + base);
    float4 q = make_float4(o4.x + p.x, o4.y + p.y, o4.z + p.z, o4.w + p.w);
    *(ushort4*)(qb + base) = f2b4(q);
  }
}

// ---------------------------------------------------------------------------
extern "C" void kernel_launch(void* const* d_in, const int* in_sizes, int n_in,
                              void* d_out, int out_size, void* d_ws, size_t ws_size,
                              hipStream_t stream)
{
  const float* src[3] = {(const float*)d_in[0], (const float*)d_in[1], (const float*)d_in[2]};
  const float* pin[3] = {(const float*)d_in[3], (const float*)d_in[4], (const float*)d_in[5]};
  const float* lvl_emb = (const float*)d_in[6];
  const float* off_w = (const float*)d_in[7];
  const float* off_b = (const float*)d_in[8];
  const float* aw_w  = (const float*)d_in[9];
  const float* aw_b  = (const float*)d_in[10];
  const float* val_w = (const float*)d_in[11];
  const float* val_b = (const float*)d_in[12];
  const float* out_w = (const float*)d_in[13];
  const float* out_b = (const float*)d_in[14];
  const float* ln1_g = (const float*)d_in[15];
  const float* ln1_b = (const float*)d_in[16];
  const float* ffn1_w = (const float*)d_in[17];
  const float* ffn1_b = (const float*)d_in[18];
  const float* ffn2_w = (const float*)d_in[19];
  const float* ffn2_b = (const float*)d_in[20];
  const float* ln2_g = (const float*)d_in[21];
  const float* ln2_b = (const float*)d_in[22];

  float* x = (float*)d_out;                                  // (B,QTOT,256) f32

  char* wsp = (char*)d_ws;
  float* posb  = (float*)wsp;  wsp += (size_t)BQ * 256 * 4;
  float* valb  = (float*)wsp;  wsp += (size_t)BQ * 256 * 4;   // out-proj / ffn2 f32
  float* offaw = (float*)wsp;  wsp += (size_t)BQ * NOA * 4;   // 24.8 MB
  unsigned short* valb16 = (unsigned short*)wsp; wsp += (size_t)BQ * 256 * 2;
  unsigned short* attnb  = (unsigned short*)wsp; wsp += (size_t)BQ * 256 * 2;
  unsigned short* hb = (unsigned short*)offaw;  // alias offaw+valb16+attnb (44MB<46.8MB)
  unsigned short* xb = (unsigned short*)wsp; wsp += (size_t)BQ * 256 * 2;
  unsigned short* qb = (unsigned short*)wsp; wsp += (size_t)BQ * 256 * 2;

  unsigned short* vWb  = (unsigned short*)wsp; wsp += (size_t)6 * 256 * 256 * 2;
  unsigned short* oaWb = (unsigned short*)wsp; wsp += (size_t)6 * NOA * 256 * 2;
  unsigned short* uWb  = (unsigned short*)wsp; wsp += (size_t)6 * 256 * 256 * 2;
  unsigned short* f1Wb = (unsigned short*)wsp; wsp += (size_t)6 * 1024 * 256 * 2;
  unsigned short* f2Wb = (unsigned short*)wsp; wsp += (size_t)6 * 256 * 1024 * 2;
  float* oaBias = (float*)wsp; wsp += (size_t)6 * NOA * 4;
  wsp += 65536;   // slack for masked-N OOB staging reads

  conv_b<<<(6 * 65536 / 4 + 255) / 256, 256, 0, stream>>>(val_w, vWb, 6 * 65536 / 4);
  conv_b<<<(6 * 65536 / 4 + 255) / 256, 256, 0, stream>>>(out_w, uWb, 6 * 65536 / 4);
  conv_b<<<(6 * 262144 / 4 + 255) / 256, 256, 0, stream>>>(ffn1_w, f1Wb, 6 * 262144 / 4);
  conv_b<<<(6 * 262144 / 4 + 255) / 256, 256, 0, stream>>>(ffn2_w, f2Wb, 6 * 262144 / 4);
  pack_oa<<<(6 * NOA * 64 + 255) / 256, 256, 0, stream>>>(off_w, aw_w, oaWb);
  pack_oa_bias<<<(6 * NOA + 255) / 256, 256, 0, stream>>>(off_b, aw_b, oaBias);

  const int HWs[3] = {4096, 1024, 256};
  const int starts[3] = {0, 4096, 5120};
  for (int l = 0; l < 3; l++) {
    dim3 g(HWs[l] / 32, DMM / 32, BB), blk(32, 8);
    transpose_in<<<g, blk, 0, stream>>>(src[l], nullptr, x, HWs[l], starts[l]);
    transpose_in<<<g, blk, 0, stream>>>(pin[l], lvl_emb + l * 256, posb, HWs[l], starts[l]);
  }
  prep<<<(BQ * 256 / 4 + 255) / 256, 256, 0, stream>>>(x, posb, xb, qb, BQ * 256 / 4);

  for (int i = 0; i < 6; i++) {
    gemm_bf<<<dim3(BQ / 128, 2), 256, 0, stream>>>(xb, vWb + (size_t)i * 65536,
        val_b + i * 256, valb16, BQ, 256, 256, 2);
    gemm_bf<<<dim3(BQ / 128, 3), 256, 0, stream>>>(qb, oaWb + (size_t)i * NOA * 256,
        oaBias + i * NOA, offaw, BQ, NOA, 256, 0);
    msda_sample<<<BQ / 4, 256, 0, stream>>>(valb16, offaw, attnb);
    gemm_bf<<<dim3(BQ / 128, 2), 256, 0, stream>>>(attnb, uWb + (size_t)i * 65536,
        out_b + i * 256, valb, BQ, 256, 256, 0);
    add_ln4<<<BQ / 4, 256, 0, stream>>>(x, valb, ln1_g + i * 256, ln1_b + i * 256,
        xb, nullptr, nullptr);
    gemm_bf<<<dim3(BQ / 128, 8), 256, 0, stream>>>(xb, f1Wb + (size_t)i * 262144,
        ffn1_b + i * 1024, hb, BQ, 1024, 256, 1 | 2);
    gemm_bf<<<dim3(BQ / 128, 2), 256, 0, stream>>>(hb, f2Wb + (size_t)i * 262144,
        ffn2_b + i * 256, valb, BQ, 256, 1024, 0);
    add_ln4<<<BQ / 4, 256, 0, stream>>>(x, valb, ln2_g + i * 256, ln2_b + i * 256,
        xb, posb, qb);
  }
}